// Round 9
// baseline (141.412 us; speedup 1.0000x reference)
//
#include <hip/hip_runtime.h>
#include <hip/hip_bf16.h>
#include <stdint.h>

// Problem dims (fixed by reference setup_inputs)
#define B_SZ 128
#define R_SZ 36       // real regions per image
#define RP_SZ 48      // padded regions (dup row 35) -> multiple of 16
#define W_SZ 60       // real words per caption
#define WP_SZ 64      // padded words (dup word 59, masked in epilogue)
#define D_SZ 1024
#define MARGIN 0.2f

#define ATILE (192 * 64)   // bf16 elems per A K-tile
#define BTILE (128 * 64)   // bf16 elems per B K-tile (BN=128: 2 captions)

typedef __attribute__((ext_vector_type(8))) short short8;   // 8 bf16 (MFMA A/B frag)
typedef __attribute__((ext_vector_type(4))) float f32x4;    // MFMA C/D frag

typedef __attribute__((address_space(3))) unsigned int lds_u32;
typedef const __attribute__((address_space(1))) unsigned int glb_u32;

__device__ __forceinline__ void gload16(const unsigned short* g, unsigned short* l) {
    __builtin_amdgcn_global_load_lds((glb_u32*)g, (lds_u32*)l, 16, 0, 0);
}

__device__ __forceinline__ unsigned short f2bf(float f) {
    union { float f; uint32_t u; } x; x.f = f;
    uint32_t u = x.u;
    uint32_t r = (u + 0x7FFFu + ((u >> 16) & 1u)) >> 16;   // RNE bf16
    return (unsigned short)r;
}

// Fused fp32 -> bf16 convert + row-pad for BOTH tensors in one launch.
__global__ __launch_bounds__(256) void convert_pad_kernel(
        const float* __restrict__ im, const float* __restrict__ s,
        unsigned short* __restrict__ imb, unsigned short* __restrict__ sb) {
    const int n4_im = B_SZ * RP_SZ * D_SZ / 4;
    const int n4_s  = B_SZ * WP_SZ * D_SZ / 4;
    int i = blockIdx.x * 256 + threadIdx.x;
    const float* src;
    unsigned short* dst;
    int srcIdx;
    if (i < n4_im) {
        int idx = i * 4;
        int d  = idx & (D_SZ - 1);
        int rj = idx >> 10;
        int r  = rj % RP_SZ;
        int j  = rj / RP_SZ;
        int rs = r < R_SZ ? r : R_SZ - 1;
        src = im; dst = imb + idx;
        srcIdx = ((j * R_SZ + rs) << 10) + d;
    } else {
        int i2 = i - n4_im;
        if (i2 >= n4_s) return;
        int idx = i2 * 4;
        int d  = idx & (D_SZ - 1);
        int rj = idx >> 10;
        int r  = rj & (WP_SZ - 1);
        int j  = rj >> 6;
        int rs = r < W_SZ ? r : W_SZ - 1;
        src = s; dst = sb + idx;
        srcIdx = ((j * W_SZ + rs) << 10) + d;
    }
    const float4 v = *reinterpret_cast<const float4*>(src + srcIdx);
    ushort4 o;
    o.x = f2bf(v.x); o.y = f2bf(v.y); o.z = f2bf(v.z); o.w = f2bf(v.w);
    *reinterpret_cast<ushort4*>(dst) = o;
}

// Fused GEMM + MISA epilogue.
// Round-9 geometry: block 192x128 (4 images x 2 captions), BK=64, 4 waves
// (2Mx2N) of the validated 96x64 per-wave tile (acc[6][4], 16x16x32).
// LDS = dbuf(A 48 KB + B 32 KB) = 80 KB -> TWO blocks per CU (the m114
// mechanism: the other block's MFMA cluster hides this block's LDS-read
// burst and barrier drain; all 1-block/CU designs measured zero overlap).
// Schedule per K-tile (validated round 8): issue all 20 ds_read_b128 ->
// stage kt+1 (10 gload_lds) -> 48 MFMAs (compiler-counted lgkmcnt) ->
// vmcnt(0) + single s_barrier. XOR slot-swizzle (0 bank conflicts).
__global__ __launch_bounds__(256, 2) void scores_kernel(
        const unsigned short* __restrict__ imb,   // [128][48][1024] bf16 (padded)
        const unsigned short* __restrict__ sb,    // [128][64][1024] bf16 (padded)
        const int* __restrict__ s_l,
        float* __restrict__ S)                    // [j][i]
{
    __shared__ unsigned short As[2 * ATILE];   // 48 KB
    __shared__ unsigned short Bs[2 * BTILE];   // 32 KB

    const int tid  = threadIdx.x;
    const int wid  = tid >> 6;        // 0..3
    const int lane = tid & 63;
    const int l15  = lane & 15;
    const int kgrp = lane >> 4;       // 0..3
    const int wr   = wid >> 1;        // 0..1 (M)
    const int wc   = wid & 1;         // 0..1 (N)

    // XCD-chunked swizzle over 2048 blocks (it-major chunks: B panel per XCD L2)
    int bid = blockIdx.x;
    int swz = (bid & 7) * 256 + (bid >> 3);
    int jt = swz & 31;                // 0..31 (4 images each)
    int it = swz >> 5;                // 0..63 (2 captions each)

    // staging: 8 lanes per 128B row-segment, pre-swizzled source slot
    const int lrow = lane >> 3;                   // 0..7 == row&7 of staged row
    const int slot = (lane & 7) ^ lrow;           // LDS[row][s] = G[row][s^(row&7)]

    // A: 24 chunks (8 rows x 64 K), 6 per wave; B: 16 chunks, 4 per wave
    const unsigned short* gA[6];
    int aoff[6];
#pragma unroll
    for (int c = 0; c < 6; ++c) {
        int chunk = wid + c * 4;                  // 0..23
        int row = chunk * 8 + lrow;               // 0..191
        gA[c] = imb + (size_t)(jt * 192 + row) * D_SZ + slot * 8;
        aoff[c] = chunk * 512 + lane * 8;         // linear: base + lane*16B
    }
    const unsigned short* gB[4];
    int boff[4];
#pragma unroll
    for (int c = 0; c < 4; ++c) {
        int chunk = wid + c * 4;                  // 0..15
        int row = chunk * 8 + lrow;               // 0..127
        gB[c] = sb + (size_t)(it * 128 + row) * D_SZ + slot * 8;
        boff[c] = chunk * 512 + lane * 8;
    }

    // ds_read addressing: elem = row*64 + ((k2*4+kgrp)^(l15&7))*8; k2=1 -> ^32
    const int rsw = l15 & 7;
    const int k0off = (kgrp ^ rsw) * 8;
    int abase[6];
#pragma unroll
    for (int rf = 0; rf < 6; ++rf)
        abase[rf] = (wr * 96 + rf * 16 + l15) * 64 + k0off;
    int bbase[4];
#pragma unroll
    for (int cf = 0; cf < 4; ++cf)
        bbase[cf] = (wc * 64 + cf * 16 + l15) * 64 + k0off;

    f32x4 acc[6][4] = {};

    // prologue: stage tile 0 into buffer 0
#pragma unroll
    for (int c = 0; c < 6; ++c) gload16(gA[c], As + aoff[c]);
#pragma unroll
    for (int c = 0; c < 4; ++c) gload16(gB[c], Bs + boff[c]);
    asm volatile("s_waitcnt vmcnt(0)" ::: "memory");
    __builtin_amdgcn_s_barrier();

#pragma unroll 2
    for (int kt = 0; kt < 16; ++kt) {
        const int cur = kt & 1;
        const unsigned short* Ac = As + cur * ATILE;
        const unsigned short* Bc = Bs + cur * BTILE;

        // issue ALL reads for tile kt (both k2 slices): 20 ds_read_b128
        short8 afr[2][6], bfr[2][4];
#pragma unroll
        for (int k2 = 0; k2 < 2; ++k2) {
#pragma unroll
            for (int rf = 0; rf < 6; ++rf)
                afr[k2][rf] = *reinterpret_cast<const short8*>(Ac + (abase[rf] ^ (k2 * 32)));
#pragma unroll
            for (int cf = 0; cf < 4; ++cf)
                bfr[k2][cf] = *reinterpret_cast<const short8*>(Bc + (bbase[cf] ^ (k2 * 32)));
        }

        // stage tile kt+1 into the other buffer (all kt-1 reads retired
        // before the end-of-kt-1 barrier: consumed by kt-1's MFMAs)
        if (kt < 15) {
            const int ko = (kt + 1) * 64;
            unsigned short* Ad = As + (cur ^ 1) * ATILE;
            unsigned short* Bd = Bs + (cur ^ 1) * BTILE;
#pragma unroll
            for (int c = 0; c < 6; ++c) gload16(gA[c] + ko, Ad + aoff[c]);
#pragma unroll
            for (int c = 0; c < 4; ++c) gload16(gB[c] + ko, Bd + boff[c]);
        }

        // MFMAs: no explicit lgkm drain -- compiler emits counted lgkmcnt per
        // fragment dependency; the co-resident block fills the other pipe.
        __builtin_amdgcn_s_setprio(1);
#pragma unroll
        for (int k2 = 0; k2 < 2; ++k2)
#pragma unroll
            for (int rf = 0; rf < 6; ++rf)
#pragma unroll
                for (int cf = 0; cf < 4; ++cf)
                    acc[rf][cf] = __builtin_amdgcn_mfma_f32_16x16x32_bf16(
                        afr[k2][rf], bfr[k2][cf], acc[rf][cf], 0, 0, 0);
        __builtin_amdgcn_s_setprio(0);

        if (kt < 15) {
            asm volatile("s_waitcnt vmcnt(0)" ::: "memory");  // tile kt+1 staged
            __builtin_amdgcn_s_barrier();                     // dbuf handoff
        }
    }

    // Epilogue: wave (wr,wc) owns caption i = it*2+wc, images j = jt*4 + wr*2 + {0,1}.
    // C frag layout: col = l15 (word), row = kgrp*4 + e (region).
    const int i_cap = it * 2 + wc;
    const int nw = s_l[i_cap];
    const float inv = 1.0f / (float)nw;
#pragma unroll
    for (int h = 0; h < 2; ++h) {       // image half: frags rf = h*3 .. h*3+2 (48 rows)
        float sum = 0.0f;
#pragma unroll
        for (int cf = 0; cf < 4; ++cf) {
            float m = acc[h * 3][cf][0];
#pragma unroll
            for (int rf = h * 3; rf < h * 3 + 3; ++rf)
#pragma unroll
                for (int e = 0; e < 4; ++e)
                    m = fmaxf(m, acc[rf][cf][e]);
            m = fmaxf(m, __shfl_xor(m, 16));
            m = fmaxf(m, __shfl_xor(m, 32));
            int wv = cf * 16 + l15;
            if (wv < nw) sum += m;
        }
        sum += __shfl_xor(sum, 1);
        sum += __shfl_xor(sum, 2);
        sum += __shfl_xor(sum, 4);
        sum += __shfl_xor(sum, 8);
        if (lane == 0) {
            int j_img = jt * 4 + wr * 2 + h;
            S[j_img * B_SZ + i_cap] = sum * inv;
        }
    }
}

// Contrastive loss over the 128x128 score matrix, single block
__global__ __launch_bounds__(256) void loss_kernel(
        const float* __restrict__ S, float* __restrict__ out) {
    __shared__ float diag[B_SZ];
    __shared__ float red[256];
    int t = threadIdx.x;
    if (t < B_SZ) diag[t] = S[t * (B_SZ + 1)];
    __syncthreads();
    float acc = 0.0f;
    for (int idx = t; idx < B_SZ * B_SZ; idx += 256) {
        int a = idx >> 7, b = idx & (B_SZ - 1);
        if (a != b) {
            float v = S[idx];
            acc += fmaxf(MARGIN + v - diag[a], 0.0f)
                 + fmaxf(MARGIN + v - diag[b], 0.0f);
        }
    }
    red[t] = acc;
    __syncthreads();
    for (int s = 128; s > 0; s >>= 1) {
        if (t < s) red[t] += red[t + s];
        __syncthreads();
    }
    if (t == 0) out[0] = red[0];
}

extern "C" void kernel_launch(void* const* d_in, const int* in_sizes, int n_in,
                              void* d_out, int out_size, void* d_ws, size_t ws_size,
                              hipStream_t stream) {
    const float* im  = (const float*)d_in[0];
    const float* s   = (const float*)d_in[1];
    const int*   s_l = (const int*)d_in[2];
    // d_in[3] (x) unused by the math

    const int n_im_pad = B_SZ * RP_SZ * D_SZ;   // 6,291,456
    const int n_s_pad  = B_SZ * WP_SZ * D_SZ;   // 8,388,608

    unsigned short* imb = (unsigned short*)d_ws;
    unsigned short* sb  = imb + n_im_pad;
    float* S = (float*)(sb + n_s_pad);          // 128*128 floats

    const int n4_total = (n_im_pad + n_s_pad) / 4;
    convert_pad_kernel<<<(n4_total + 255) / 256, 256, 0, stream>>>(im, s, imb, sb);

    scores_kernel<<<2048, 256, 0, stream>>>(imb, sb, s_l, S);

    loss_kernel<<<1, 256, 0, stream>>>(S, (float*)d_out);
}

// Round 10
// 139.660 us; speedup vs baseline: 1.0125x; 1.0125x over previous
//
#include <hip/hip_runtime.h>
#include <hip/hip_bf16.h>
#include <stdint.h>

// Problem dims (fixed by reference setup_inputs)
#define B_SZ 128
#define R_SZ 36       // real regions per image
#define RP_SZ 48      // padded regions (dup row 35) -> multiple of 16
#define W_SZ 60       // real words per caption
#define WP_SZ 64      // padded words (dup word 59, masked in epilogue)
#define D_SZ 1024
#define MARGIN 0.2f

#define ATILE (192 * 64)   // bf16 elems per A K-tile
#define BTILE (256 * 64)   // bf16 elems per B K-tile

typedef __attribute__((ext_vector_type(8))) short short8;   // 8 bf16 (MFMA A/B frag)
typedef __attribute__((ext_vector_type(4))) float f32x4;    // MFMA C/D frag

typedef __attribute__((address_space(3))) unsigned int lds_u32;
typedef const __attribute__((address_space(1))) unsigned int glb_u32;

__device__ __forceinline__ void gload16(const unsigned short* g, unsigned short* l) {
    __builtin_amdgcn_global_load_lds((glb_u32*)g, (lds_u32*)l, 16, 0, 0);
}

__device__ __forceinline__ unsigned short f2bf(float f) {
    union { float f; uint32_t u; } x; x.f = f;
    uint32_t u = x.u;
    uint32_t r = (u + 0x7FFFu + ((u >> 16) & 1u)) >> 16;   // RNE bf16
    return (unsigned short)r;
}

// Fused fp32 -> bf16 convert + row-pad for BOTH tensors in one launch.
__global__ __launch_bounds__(256) void convert_pad_kernel(
        const float* __restrict__ im, const float* __restrict__ s,
        unsigned short* __restrict__ imb, unsigned short* __restrict__ sb) {
    const int n4_im = B_SZ * RP_SZ * D_SZ / 4;
    const int n4_s  = B_SZ * WP_SZ * D_SZ / 4;
    int i = blockIdx.x * 256 + threadIdx.x;
    const float* src;
    unsigned short* dst;
    int srcIdx;
    if (i < n4_im) {
        int idx = i * 4;
        int d  = idx & (D_SZ - 1);
        int rj = idx >> 10;
        int r  = rj % RP_SZ;
        int j  = rj / RP_SZ;
        int rs = r < R_SZ ? r : R_SZ - 1;
        src = im; dst = imb + idx;
        srcIdx = ((j * R_SZ + rs) << 10) + d;
    } else {
        int i2 = i - n4_im;
        if (i2 >= n4_s) return;
        int idx = i2 * 4;
        int d  = idx & (D_SZ - 1);
        int rj = idx >> 10;
        int r  = rj & (WP_SZ - 1);
        int j  = rj >> 6;
        int rs = r < W_SZ ? r : W_SZ - 1;
        src = s; dst = sb + idx;
        srcIdx = ((j * W_SZ + rs) << 10) + d;
    }
    const float4 v = *reinterpret_cast<const float4*>(src + srcIdx);
    ushort4 o;
    o.x = f2bf(v.x); o.y = f2bf(v.y); o.z = f2bf(v.z); o.w = f2bf(v.w);
    *reinterpret_cast<ushort4*>(dst) = o;
}

// Fused GEMM + MISA epilogue, 2-phase K-tile with COUNTED vmcnt (T3+T4):
// Geometry validated R2-R9: block 192x256, BK=64, 8 waves (2Mx4N), per-wave
// 96x64 (acc[6][4], 16x16x32), dbuf LDS 112 KB, XOR slot-swizzle, 1 block/CU.
// Phase split per wave's cf-half; B's phase-halves are the even/odd 32-row
// quads (chunk quads), so each half is freed at a phase barrier:
//   ph0: stage BO(kt+1)->B[nxt].odd | read A(12)+BE-cf01(4) | 24 MFMA | barrier
//        (frees A[cur] + Beven[cur])
//   ph1: stage A(kt+2)->A[cur], BE(kt+2)->B[cur].even | read BO-cf23(4)
//        | 24 MFMA | vmcnt(5) | barrier
// Every staging load gets >=3 phases of flight; rendezvous is counted (5),
// never 0 (m218/m233 mechanism). Tail: staged tile index clamped to 15
// (redundant loads into dead buffers -> uniform vmcnt counts, no branches).
__global__ __launch_bounds__(512, 2) void scores_kernel(
        const unsigned short* __restrict__ imb,   // [128][48][1024] bf16 (padded)
        const unsigned short* __restrict__ sb,    // [128][64][1024] bf16 (padded)
        const int* __restrict__ s_l,
        float* __restrict__ S)                    // [j][i]
{
    __shared__ unsigned short As[2 * ATILE];
    __shared__ unsigned short Bs[2 * BTILE];

    const int tid  = threadIdx.x;
    const int wid  = tid >> 6;        // 0..7
    const int lane = tid & 63;
    const int l15  = lane & 15;
    const int kgrp = lane >> 4;       // 0..3
    const int wr   = wid >> 2;        // 0..1 (M)
    const int wc   = wid & 3;         // 0..3 (N)

    // Supertile XCD swizzle: XCD k owns it in [4k,4k+4); within XCD iterate
    // jt-groups of 8 across the 4 its (A-panel L2 reuse x4, B stays local).
    int bid = blockIdx.x;
    int k8  = bid & 7;                // XCD
    int w   = bid >> 3;               // 0..127 within XCD
    int jtg = w >> 5;                 // 0..3  (jt group of 8)
    int sw  = w & 31;
    int it  = k8 * 4 + (sw >> 3);     // 0..31 (4 captions each)
    int jt  = jtg * 8 + (sw & 7);     // 0..31 (4 images each)

    // staging: 8 lanes per 128B row-segment, pre-swizzled source slot
    const int lrow = lane >> 3;                   // 0..7 == row&7 of staged row
    const int slot = (lane & 7) ^ lrow;           // LDS[row][s] = G[row][s^(row&7)]

    // A: 24 chunks (1 KB each), 3 per wave
    const unsigned short* gA[3];
    int aoff[3];
#pragma unroll
    for (int c = 0; c < 3; ++c) {
        int chunk = wid + c * 8;                  // 0..23
        int row = chunk * 8 + lrow;               // 0..191
        gA[c] = imb + (size_t)(jt * 192 + row) * D_SZ + slot * 8;
        aoff[c] = chunk * 512 + lane * 8;         // linear: base + lane*16B
    }
    // B even-quad chunks (rows {0-31,64-95,128-159,192-223}): 16 chunks, 2/wave
    // B odd-quad = even chunk + 4 (rows {32-63,96-127,160-191,224-255})
    const unsigned short* gBE[2], *gBO[2];
    int beoff[2], booff[2];
#pragma unroll
    for (int c = 0; c < 2; ++c) {
        int chunkE = 8 * (wid >> 2) + 16 * c + (wid & 3);   // even quads
        int chunkO = chunkE + 4;                            // odd quads
        gBE[c] = sb + (size_t)(it * 256 + chunkE * 8 + lrow) * D_SZ + slot * 8;
        gBO[c] = sb + (size_t)(it * 256 + chunkO * 8 + lrow) * D_SZ + slot * 8;
        beoff[c] = chunkE * 512 + lane * 8;
        booff[c] = chunkO * 512 + lane * 8;
    }

    // ds_read addressing: elem = row*64 + ((k2*4+kgrp)^(l15&7))*8; k2=1 -> ^32
    const int rsw = l15 & 7;
    const int k0off = (kgrp ^ rsw) * 8;
    int abase[6];
#pragma unroll
    for (int rf = 0; rf < 6; ++rf)
        abase[rf] = (wr * 96 + rf * 16 + l15) * 64 + k0off;
    int bbase[4];
#pragma unroll
    for (int cf = 0; cf < 4; ++cf)
        bbase[cf] = (wc * 64 + cf * 16 + l15) * 64 + k0off;
    // cf 0,1 rows (wc*64+0..31) lie in even quads; cf 2,3 in odd quads.

    f32x4 acc[6][4] = {};

    // prologue: tile 0 fully; tile 1 A+Beven (Bodd(1) staged in ph0 of kt=0)
#pragma unroll
    for (int c = 0; c < 3; ++c) gload16(gA[c], As + aoff[c]);
#pragma unroll
    for (int c = 0; c < 2; ++c) gload16(gBE[c], Bs + beoff[c]);
#pragma unroll
    for (int c = 0; c < 2; ++c) gload16(gBO[c], Bs + booff[c]);
#pragma unroll
    for (int c = 0; c < 3; ++c) gload16(gA[c] + 64, As + ATILE + aoff[c]);
#pragma unroll
    for (int c = 0; c < 2; ++c) gload16(gBE[c] + 64, Bs + BTILE + beoff[c]);
    asm volatile("s_waitcnt vmcnt(5)" ::: "memory");   // tile 0 resident
    __builtin_amdgcn_s_barrier();

#pragma unroll 2
    for (int kt = 0; kt < 16; ++kt) {
        const int cur = kt & 1;
        const int nxt = cur ^ 1;
        const unsigned short* Ac = As + cur * ATILE;
        const unsigned short* Bc = Bs + cur * BTILE;

        // ===== phase 0: cf 0-1 =====
        {   // stage Bodd(kt+1) -> B[nxt] odd quads (slot freed at ph1(kt-1))
            const int ko = (kt + 1 < 16 ? kt + 1 : 15) * 64;
#pragma unroll
            for (int c = 0; c < 2; ++c)
                gload16(gBO[c] + ko, Bs + nxt * BTILE + booff[c]);
        }
        short8 afr[2][6], bfr0[2][2];
#pragma unroll
        for (int k2 = 0; k2 < 2; ++k2) {
#pragma unroll
            for (int rf = 0; rf < 6; ++rf)
                afr[k2][rf] = *reinterpret_cast<const short8*>(Ac + (abase[rf] ^ (k2 * 32)));
#pragma unroll
            for (int cf = 0; cf < 2; ++cf)
                bfr0[k2][cf] = *reinterpret_cast<const short8*>(Bc + (bbase[cf] ^ (k2 * 32)));
        }
        __builtin_amdgcn_s_setprio(1);
#pragma unroll
        for (int k2 = 0; k2 < 2; ++k2)
#pragma unroll
            for (int rf = 0; rf < 6; ++rf)
#pragma unroll
                for (int cf = 0; cf < 2; ++cf)
                    acc[rf][cf] = __builtin_amdgcn_mfma_f32_16x16x32_bf16(
                        afr[k2][rf], bfr0[k2][cf], acc[rf][cf], 0, 0, 0);
        __builtin_amdgcn_s_setprio(0);
        __builtin_amdgcn_s_barrier();   // frees A[cur] + Beven[cur]

        // ===== phase 1: cf 2-3 =====
        {   // stage A(kt+2) -> A[cur], Beven(kt+2) -> B[cur] even (just freed)
            const int ko = (kt + 2 < 16 ? kt + 2 : 15) * 64;
#pragma unroll
            for (int c = 0; c < 3; ++c)
                gload16(gA[c] + ko, As + cur * ATILE + aoff[c]);
#pragma unroll
            for (int c = 0; c < 2; ++c)
                gload16(gBE[c] + ko, Bs + cur * BTILE + beoff[c]);
        }
        short8 bfr1[2][2];
#pragma unroll
        for (int k2 = 0; k2 < 2; ++k2)
#pragma unroll
            for (int cf = 0; cf < 2; ++cf)
                bfr1[k2][cf] = *reinterpret_cast<const short8*>(Bc + (bbase[cf + 2] ^ (k2 * 32)));
        __builtin_amdgcn_s_setprio(1);
#pragma unroll
        for (int k2 = 0; k2 < 2; ++k2)
#pragma unroll
            for (int rf = 0; rf < 6; ++rf)
#pragma unroll
                for (int cf = 0; cf < 2; ++cf)
                    acc[rf][cf + 2] = __builtin_amdgcn_mfma_f32_16x16x32_bf16(
                        afr[k2][rf], bfr1[k2][cf], acc[rf][cf + 2], 0, 0, 0);
        __builtin_amdgcn_s_setprio(0);
        // counted rendezvous: tile kt+1 resident (5 newest = A(kt+2)+BE(kt+2))
        asm volatile("s_waitcnt vmcnt(5)" ::: "memory");
        __builtin_amdgcn_s_barrier();
    }

    // Epilogue: wave (wr,wc) owns caption i = it*4+wc, images j = jt*4 + wr*2 + {0,1}.
    // C frag layout: col = l15 (word), row = kgrp*4 + e (region).
    const int i_cap = it * 4 + wc;
    const int nw = s_l[i_cap];
    const float inv = 1.0f / (float)nw;
#pragma unroll
    for (int h = 0; h < 2; ++h) {       // image half: frags rf = h*3 .. h*3+2 (48 rows)
        float sum = 0.0f;
#pragma unroll
        for (int cf = 0; cf < 4; ++cf) {
            float m = acc[h * 3][cf][0];
#pragma unroll
            for (int rf = h * 3; rf < h * 3 + 3; ++rf)
#pragma unroll
                for (int e = 0; e < 4; ++e)
                    m = fmaxf(m, acc[rf][cf][e]);
            m = fmaxf(m, __shfl_xor(m, 16));
            m = fmaxf(m, __shfl_xor(m, 32));
            int wv = cf * 16 + l15;
            if (wv < nw) sum += m;
        }
        sum += __shfl_xor(sum, 1);
        sum += __shfl_xor(sum, 2);
        sum += __shfl_xor(sum, 4);
        sum += __shfl_xor(sum, 8);
        if (lane == 0) {
            int j_img = jt * 4 + wr * 2 + h;
            S[j_img * B_SZ + i_cap] = sum * inv;
        }
    }
}

// Contrastive loss over the 128x128 score matrix, single block
__global__ __launch_bounds__(256) void loss_kernel(
        const float* __restrict__ S, float* __restrict__ out) {
    __shared__ float diag[B_SZ];
    __shared__ float red[256];
    int t = threadIdx.x;
    if (t < B_SZ) diag[t] = S[t * (B_SZ + 1)];
    __syncthreads();
    float acc = 0.0f;
    for (int idx = t; idx < B_SZ * B_SZ; idx += 256) {
        int a = idx >> 7, b = idx & (B_SZ - 1);
        if (a != b) {
            float v = S[idx];
            acc += fmaxf(MARGIN + v - diag[a], 0.0f)
                 + fmaxf(MARGIN + v - diag[b], 0.0f);
        }
    }
    red[t] = acc;
    __syncthreads();
    for (int s = 128; s > 0; s >>= 1) {
        if (t < s) red[t] += red[t + s];
        __syncthreads();
    }
    if (t == 0) out[0] = red[0];
}

extern "C" void kernel_launch(void* const* d_in, const int* in_sizes, int n_in,
                              void* d_out, int out_size, void* d_ws, size_t ws_size,
                              hipStream_t stream) {
    const float* im  = (const float*)d_in[0];
    const float* s   = (const float*)d_in[1];
    const int*   s_l = (const int*)d_in[2];
    // d_in[3] (x) unused by the math

    const int n_im_pad = B_SZ * RP_SZ * D_SZ;   // 6,291,456
    const int n_s_pad  = B_SZ * WP_SZ * D_SZ;   // 8,388,608

    unsigned short* imb = (unsigned short*)d_ws;
    unsigned short* sb  = imb + n_im_pad;
    float* S = (float*)(sb + n_s_pad);          // 128*128 floats

    const int n4_total = (n_im_pad + n_s_pad) / 4;
    convert_pad_kernel<<<(n4_total + 255) / 256, 256, 0, stream>>>(im, s, imb, sb);

    scores_kernel<<<1024, 512, 0, stream>>>(imb, sb, s_l, S);

    loss_kernel<<<1, 256, 0, stream>>>(S, (float*)d_out);
}

// Round 11
// 130.433 us; speedup vs baseline: 1.0842x; 1.0707x over previous
//
#include <hip/hip_runtime.h>
#include <hip/hip_bf16.h>
#include <stdint.h>

// Problem dims (fixed by reference setup_inputs)
#define B_SZ 128
#define R_SZ 36       // real regions per image
#define RP_SZ 48      // padded regions (dup row 35) -> multiple of 16
#define W_SZ 60       // real words per caption
#define WP_SZ 64      // padded words (dup word 59, masked in epilogue)
#define D_SZ 1024
#define MARGIN 0.2f

#define ATILE (192 * 64)   // bf16 elems per A K-tile
#define BTILE (256 * 64)   // bf16 elems per B K-tile

typedef __attribute__((ext_vector_type(8))) short short8;   // 8 bf16 (MFMA A/B frag)
typedef __attribute__((ext_vector_type(4))) float f32x4;    // MFMA C/D frag

typedef __attribute__((address_space(3))) unsigned int lds_u32;
typedef const __attribute__((address_space(1))) unsigned int glb_u32;

__device__ __forceinline__ void gload16(const unsigned short* g, unsigned short* l) {
    __builtin_amdgcn_global_load_lds((glb_u32*)g, (lds_u32*)l, 16, 0, 0);
}

__device__ __forceinline__ unsigned short f2bf(float f) {
    union { float f; uint32_t u; } x; x.f = f;
    uint32_t u = x.u;
    uint32_t r = (u + 0x7FFFu + ((u >> 16) & 1u)) >> 16;   // RNE bf16
    return (unsigned short)r;
}

// Fused fp32 -> bf16 convert + row-pad for BOTH tensors in one launch.
__global__ __launch_bounds__(256) void convert_pad_kernel(
        const float* __restrict__ im, const float* __restrict__ s,
        unsigned short* __restrict__ imb, unsigned short* __restrict__ sb) {
    const int n4_im = B_SZ * RP_SZ * D_SZ / 4;
    const int n4_s  = B_SZ * WP_SZ * D_SZ / 4;
    int i = blockIdx.x * 256 + threadIdx.x;
    const float* src;
    unsigned short* dst;
    int srcIdx;
    if (i < n4_im) {
        int idx = i * 4;
        int d  = idx & (D_SZ - 1);
        int rj = idx >> 10;
        int r  = rj % RP_SZ;
        int j  = rj / RP_SZ;
        int rs = r < R_SZ ? r : R_SZ - 1;
        src = im; dst = imb + idx;
        srcIdx = ((j * R_SZ + rs) << 10) + d;
    } else {
        int i2 = i - n4_im;
        if (i2 >= n4_s) return;
        int idx = i2 * 4;
        int d  = idx & (D_SZ - 1);
        int rj = idx >> 10;
        int r  = rj & (WP_SZ - 1);
        int j  = rj >> 6;
        int rs = r < W_SZ ? r : W_SZ - 1;
        src = s; dst = sb + idx;
        srcIdx = ((j * W_SZ + rs) << 10) + d;
    }
    const float4 v = *reinterpret_cast<const float4*>(src + srcIdx);
    ushort4 o;
    o.x = f2bf(v.x); o.y = f2bf(v.y); o.z = f2bf(v.z); o.w = f2bf(v.w);
    *reinterpret_cast<ushort4*>(dst) = o;
}

// Fused GEMM + MISA epilogue — slice-pipelined schedule (reads hide under MFMA):
// Geometry (validated R2-R10): block 192x256, BK=64, 8 waves (2Mx4N), per-wave
// 96x64 (acc[6][4], 16x16x32), dbuf LDS 112 KB, XOR slot-swizzle, supertile
// XCD swizzle (FETCH 205->82 MB, R10).
// Two 10-fragment slice sets (S0,S1) rotate; per tile ONE barrier:
//   top: issue s1(t) ds_reads          (serviced under MFMA s0)
//   a:   MFMA s0(t) [24]
//   b:   lgkmcnt(0)   -- ALL reads of buf[cur] retired (required before re-stage)
//   c:   vmcnt(0)     -- stage(t+1) resident (issued a full window ago: free)
//   d:   s_barrier    -- buf[cur] dead block-wide; buf[nxt] valid
//   e:   stage tile t+2 -> buf[cur]
//   f:   issue s0(t+1) ds_reads from buf[nxt]   (serviced under MFMA s1)
//   g:   MFMA s1(t) [24]
// sched_barrier(0) after top and after f pins issue order (rule 18: MFMAs are
// not ordered by asm "memory" clobbers). Tail: staged ko clamped to 15.
__global__ __launch_bounds__(512, 2) void scores_kernel(
        const unsigned short* __restrict__ imb,   // [128][48][1024] bf16 (padded)
        const unsigned short* __restrict__ sb,    // [128][64][1024] bf16 (padded)
        const int* __restrict__ s_l,
        float* __restrict__ S)                    // [j][i]
{
    __shared__ unsigned short As[2 * ATILE];
    __shared__ unsigned short Bs[2 * BTILE];

    const int tid  = threadIdx.x;
    const int wid  = tid >> 6;        // 0..7
    const int lane = tid & 63;
    const int l15  = lane & 15;
    const int kgrp = lane >> 4;       // 0..3
    const int wr   = wid >> 2;        // 0..1 (M)
    const int wc   = wid & 3;         // 0..3 (N)

    // Supertile XCD swizzle (R10-validated): XCD k owns it in [4k,4k+4);
    // within XCD iterate jt-groups of 8 across the 4 its (A-panel L2 reuse).
    int bid = blockIdx.x;
    int k8  = bid & 7;                // XCD
    int w   = bid >> 3;               // 0..127 within XCD
    int jtg = w >> 5;                 // 0..3  (jt group of 8)
    int sw  = w & 31;
    int it  = k8 * 4 + (sw >> 3);     // 0..31 (4 captions each)
    int jt  = jtg * 8 + (sw & 7);     // 0..31 (4 images each)

    // staging: 8 lanes per 128B row-segment, pre-swizzled source slot
    const int lrow = lane >> 3;                   // 0..7 == row&7 of staged row
    const int slot = (lane & 7) ^ lrow;           // LDS[row][s] = G[row][s^(row&7)]

    const unsigned short* gA[3];
    int aoff[3];
#pragma unroll
    for (int c = 0; c < 3; ++c) {
        int chunk = wid + c * 8;                  // 0..23
        int row = chunk * 8 + lrow;               // 0..191
        gA[c] = imb + (size_t)(jt * 192 + row) * D_SZ + slot * 8;
        aoff[c] = chunk * 512 + lane * 8;         // linear: base + lane*16B
    }
    const unsigned short* gB[4];
    int boff[4];
#pragma unroll
    for (int c = 0; c < 4; ++c) {
        int chunk = wid + c * 8;                  // 0..31
        int row = chunk * 8 + lrow;               // 0..255
        gB[c] = sb + (size_t)(it * 256 + row) * D_SZ + slot * 8;
        boff[c] = chunk * 512 + lane * 8;
    }

    // ds_read addressing: elem = row*64 + ((k2*4+kgrp)^(l15&7))*8; k2=1 -> ^32
    const int rsw = l15 & 7;
    const int k0off = (kgrp ^ rsw) * 8;
    int abase[6];
#pragma unroll
    for (int rf = 0; rf < 6; ++rf)
        abase[rf] = (wr * 96 + rf * 16 + l15) * 64 + k0off;
    int bbase[4];
#pragma unroll
    for (int cf = 0; cf < 4; ++cf)
        bbase[cf] = (wc * 64 + cf * 16 + l15) * 64 + k0off;

    f32x4 acc[6][4] = {};
    short8 s0a[6], s0b[4], s1a[6], s1b[4];   // two slice sets, 80 VGPRs

    // prologue: stage tile 0 -> buf0, tile 1 -> buf1
#pragma unroll
    for (int c = 0; c < 3; ++c) gload16(gA[c], As + aoff[c]);
#pragma unroll
    for (int c = 0; c < 4; ++c) gload16(gB[c], Bs + boff[c]);
#pragma unroll
    for (int c = 0; c < 3; ++c) gload16(gA[c] + 64, As + ATILE + aoff[c]);
#pragma unroll
    for (int c = 0; c < 4; ++c) gload16(gB[c] + 64, Bs + BTILE + boff[c]);
    asm volatile("s_waitcnt vmcnt(7)" ::: "memory");   // tile 0 resident
    __builtin_amdgcn_s_barrier();

    // initial s0(0) reads from buf0
#pragma unroll
    for (int rf = 0; rf < 6; ++rf)
        s0a[rf] = *reinterpret_cast<const short8*>(As + abase[rf]);
#pragma unroll
    for (int cf = 0; cf < 4; ++cf)
        s0b[cf] = *reinterpret_cast<const short8*>(Bs + bbase[cf]);

#pragma unroll 2
    for (int t = 0; t < 16; ++t) {
        const int cur = t & 1;
        const unsigned short* Ac = As + cur * ATILE;
        const unsigned short* Bc = Bs + cur * BTILE;
        const unsigned short* An = As + (cur ^ 1) * ATILE;
        const unsigned short* Bn = Bs + (cur ^ 1) * BTILE;

        // top: issue s1(t) reads (k2=1 slice) -- serviced under MFMA s0
#pragma unroll
        for (int rf = 0; rf < 6; ++rf)
            s1a[rf] = *reinterpret_cast<const short8*>(Ac + (abase[rf] ^ 32));
#pragma unroll
        for (int cf = 0; cf < 4; ++cf)
            s1b[cf] = *reinterpret_cast<const short8*>(Bc + (bbase[cf] ^ 32));
        __builtin_amdgcn_sched_barrier(0);   // pin read-issue before MFMA s0

        // a: MFMA s0(t)
        __builtin_amdgcn_s_setprio(1);
#pragma unroll
        for (int rf = 0; rf < 6; ++rf)
#pragma unroll
            for (int cf = 0; cf < 4; ++cf)
                acc[rf][cf] = __builtin_amdgcn_mfma_f32_16x16x32_bf16(
                    s0a[rf], s0b[cf], acc[rf][cf], 0, 0, 0);
        __builtin_amdgcn_s_setprio(0);

        // b: all ds reads of buf[cur] retired (s1(t) + leftovers)
        asm volatile("s_waitcnt lgkmcnt(0)" ::: "memory");
        // c: stage(t+1) resident (issued one full window ago)
        asm volatile("s_waitcnt vmcnt(0)" ::: "memory");
        // d: block-wide handoff -- buf[cur] dead, buf[nxt] valid
        __builtin_amdgcn_s_barrier();

        // e: stage tile t+2 (clamped) into buf[cur]
        {
            const int ko = (t + 2 < 16 ? t + 2 : 15) * 64;
            unsigned short* Ad = As + cur * ATILE;
            unsigned short* Bd = Bs + cur * BTILE;
#pragma unroll
            for (int c = 0; c < 3; ++c) gload16(gA[c] + ko, Ad + aoff[c]);
#pragma unroll
            for (int c = 0; c < 4; ++c) gload16(gB[c] + ko, Bd + boff[c]);
        }
        // f: issue s0(t+1) reads from buf[nxt] -- serviced under MFMA s1
#pragma unroll
        for (int rf = 0; rf < 6; ++rf)
            s0a[rf] = *reinterpret_cast<const short8*>(An + abase[rf]);
#pragma unroll
        for (int cf = 0; cf < 4; ++cf)
            s0b[cf] = *reinterpret_cast<const short8*>(Bn + bbase[cf]);
        __builtin_amdgcn_sched_barrier(0);   // pin e+f issue before MFMA s1

        // g: MFMA s1(t) (operands in regs since b)
        __builtin_amdgcn_s_setprio(1);
#pragma unroll
        for (int rf = 0; rf < 6; ++rf)
#pragma unroll
            for (int cf = 0; cf < 4; ++cf)
                acc[rf][cf] = __builtin_amdgcn_mfma_f32_16x16x32_bf16(
                    s1a[rf], s1b[cf], acc[rf][cf], 0, 0, 0);
        __builtin_amdgcn_s_setprio(0);
    }

    // Epilogue: wave (wr,wc) owns caption i = it*4+wc, images j = jt*4 + wr*2 + {0,1}.
    // C frag layout: col = l15 (word), row = kgrp*4 + e (region).
    const int i_cap = it * 4 + wc;
    const int nw = s_l[i_cap];
    const float inv = 1.0f / (float)nw;
#pragma unroll
    for (int h = 0; h < 2; ++h) {       // image half: frags rf = h*3 .. h*3+2 (48 rows)
        float sum = 0.0f;
#pragma unroll
        for (int cf = 0; cf < 4; ++cf) {
            float m = acc[h * 3][cf][0];
#pragma unroll
            for (int rf = h * 3; rf < h * 3 + 3; ++rf)
#pragma unroll
                for (int e = 0; e < 4; ++e)
                    m = fmaxf(m, acc[rf][cf][e]);
            m = fmaxf(m, __shfl_xor(m, 16));
            m = fmaxf(m, __shfl_xor(m, 32));
            int wv = cf * 16 + l15;
            if (wv < nw) sum += m;
        }
        sum += __shfl_xor(sum, 1);
        sum += __shfl_xor(sum, 2);
        sum += __shfl_xor(sum, 4);
        sum += __shfl_xor(sum, 8);
        if (lane == 0) {
            int j_img = jt * 4 + wr * 2 + h;
            S[j_img * B_SZ + i_cap] = sum * inv;
        }
    }
}

// Contrastive loss over the 128x128 score matrix, single block
__global__ __launch_bounds__(256) void loss_kernel(
        const float* __restrict__ S, float* __restrict__ out) {
    __shared__ float diag[B_SZ];
    __shared__ float red[256];
    int t = threadIdx.x;
    if (t < B_SZ) diag[t] = S[t * (B_SZ + 1)];
    __syncthreads();
    float acc = 0.0f;
    for (int idx = t; idx < B_SZ * B_SZ; idx += 256) {
        int a = idx >> 7, b = idx & (B_SZ - 1);
        if (a != b) {
            float v = S[idx];
            acc += fmaxf(MARGIN + v - diag[a], 0.0f)
                 + fmaxf(MARGIN + v - diag[b], 0.0f);
        }
    }
    red[t] = acc;
    __syncthreads();
    for (int s = 128; s > 0; s >>= 1) {
        if (t < s) red[t] += red[t + s];
        __syncthreads();
    }
    if (t == 0) out[0] = red[0];
}

extern "C" void kernel_launch(void* const* d_in, const int* in_sizes, int n_in,
                              void* d_out, int out_size, void* d_ws, size_t ws_size,
                              hipStream_t stream) {
    const float* im  = (const float*)d_in[0];
    const float* s   = (const float*)d_in[1];
    const int*   s_l = (const int*)d_in[2];
    // d_in[3] (x) unused by the math

    const int n_im_pad = B_SZ * RP_SZ * D_SZ;   // 6,291,456
    const int n_s_pad  = B_SZ * WP_SZ * D_SZ;   // 8,388,608

    unsigned short* imb = (unsigned short*)d_ws;
    unsigned short* sb  = imb + n_im_pad;
    float* S = (float*)(sb + n_s_pad);          // 128*128 floats

    const int n4_total = (n_im_pad + n_s_pad) / 4;
    convert_pad_kernel<<<(n4_total + 255) / 256, 256, 0, stream>>>(im, s, imb, sb);

    scores_kernel<<<1024, 512, 0, stream>>>(imb, sb, s_l, S);

    loss_kernel<<<1, 256, 0, stream>>>(S, (float*)d_out);
}

// Round 12
// 110.557 us; speedup vs baseline: 1.2791x; 1.1798x over previous
//
#include <hip/hip_runtime.h>
#include <hip/hip_bf16.h>
#include <stdint.h>

// Problem dims (fixed by reference setup_inputs)
#define B_SZ 128
#define R_SZ 36       // real regions per image
#define RP_SZ 48      // padded regions (dup row 35) -> multiple of 16
#define W_SZ 60       // real words per caption
#define WP_SZ 64      // padded words (dup word 59, masked in epilogue)
#define D_SZ 1024
#define MARGIN 0.2f

#define ATILE_B (192 * 64)   // BYTES per A K-tile (fp8, BK=64)
#define BTILE_B (256 * 64)   // BYTES per B K-tile

typedef __attribute__((ext_vector_type(4))) float f32x4;    // MFMA C/D frag

typedef __attribute__((address_space(3))) unsigned int lds_u32;
typedef const __attribute__((address_space(1))) unsigned int glb_u32;

__device__ __forceinline__ void gload16(const unsigned char* g, unsigned char* l) {
    __builtin_amdgcn_global_load_lds((glb_u32*)g, (lds_u32*)l, 16, 0, 0);
}

// fp32 -> fp8 e4m3 (HW cvt, RNE) + row-pad, LINEAR layout. The GEMM applies
// the LDS granule swizzle via per-lane SOURCE addresses (rule 21: dest linear).
__global__ __launch_bounds__(256) void convert_fp8_kernel(
        const float* __restrict__ im, const float* __restrict__ s,
        unsigned char* __restrict__ imb, unsigned char* __restrict__ sb) {
    const int nA = B_SZ * RP_SZ * 64;     // 16-B output granules of A
    const int nB = B_SZ * WP_SZ * 64;
    int i = blockIdx.x * 256 + threadIdx.x;
    const float* src;
    unsigned char* dst;
    if (i < nA) {
        int row = i >> 6, g = i & 63;
        int j = row / RP_SZ, r = row % RP_SZ;
        int rs = r < R_SZ ? r : R_SZ - 1;
        src = im + ((size_t)(j * R_SZ + rs) << 10) + g * 16;
        dst = imb + (size_t)i * 16;
    } else {
        int i2 = i - nA;
        if (i2 >= nB) return;
        int row = i2 >> 6, g = i2 & 63;
        int j = row >> 6, w = row & 63;
        int ws = w < W_SZ ? w : W_SZ - 1;
        src = s + ((size_t)(j * W_SZ + ws) << 10) + g * 16;
        dst = sb + (size_t)i2 * 16;
    }
    uint4 o;
    unsigned int* op = (unsigned int*)&o;
#pragma unroll
    for (int q = 0; q < 4; ++q) {
        float4 v = reinterpret_cast<const float4*>(src)[q];
        int w32 = __builtin_amdgcn_cvt_pk_fp8_f32(v.x, v.y, 0, false);
        w32 = __builtin_amdgcn_cvt_pk_fp8_f32(v.z, v.w, w32, true);
        op[q] = (unsigned int)w32;
    }
    *reinterpret_cast<uint4*>(dst) = o;
}

// Fused GEMM + MISA epilogue, fp8-e4m3, R8-validated schedule:
// Block 192x256, BK=64, 8 waves (2Mx4N), per-wave 96x64 (acc[6][4],
// mfma_f32_16x16x32_fp8_fp8 -- bf16 rate, HALF the LDS bytes).
// dbuf LDS 56 KB. Per K-tile: 20 ds_read_b64 (both k2 slices) -> stage kt+1
// (3-4 gload_lds/wave) -> 48 MFMAs (compiler-counted lgkmcnt interleaves) ->
// vmcnt(0) + single s_barrier.
// LDS rows are 64 B (16 banks apart): granule(16B) swizzle g ^= (row>>1)&3
// gives <=2-way bank access on ds_read_b64 (free) and is applied on the
// staging SOURCE as a pure lane function ((lane&3)^((lane>>3)&3)).
__global__ __launch_bounds__(512, 2) void scores_kernel(
        const unsigned char* __restrict__ imb,    // [128][48][1024] fp8 (padded)
        const unsigned char* __restrict__ sb,     // [128][64][1024] fp8 (padded)
        const int* __restrict__ s_l,
        float* __restrict__ S)                    // [j][i]
{
    __shared__ __align__(16) unsigned char As[2 * ATILE_B];   // 24 KB
    __shared__ __align__(16) unsigned char Bs[2 * BTILE_B];   // 32 KB

    const int tid  = threadIdx.x;
    const int wid  = tid >> 6;        // 0..7
    const int lane = tid & 63;
    const int l15  = lane & 15;
    const int kgrp = lane >> 4;       // 0..3
    const int wr   = wid >> 2;        // 0..1 (M)
    const int wc   = wid & 3;         // 0..3 (N)

    // Supertile XCD swizzle (R10-validated: FETCH 205->82 MB)
    int bid = blockIdx.x;
    int k8  = bid & 7;                // XCD
    int w   = bid >> 3;               // 0..127 within XCD
    int jtg = w >> 5;                 // 0..3
    int sw  = w & 31;
    int it  = k8 * 4 + (sw >> 3);     // 0..31 (4 captions each)
    int jt  = jtg * 8 + (sw & 7);     // 0..31 (4 images each)

    // staging: lane covers (row = chunk*16 + lane>>2, dest granule lane&3);
    // swizzled source granule = (lane&3) ^ ((lane>>3)&3)  [== (row>>1)&3]
    const int drow = lane >> 2;
    const int sgr  = ((lane & 3) ^ ((lane >> 3) & 3)) * 16;

    // 28 1-KB chunks (A:12, B:16); wave w stages chunks {w, w+8, w+16, w+24}
    const unsigned char* gsrc[4];
    unsigned char* gdst0[4];
    int tsz[4];
#pragma unroll
    for (int si = 0; si < 4; ++si) {
        int c = wid + si * 8;
        if (c < 12) {
            gsrc[si]  = imb + (size_t)(jt * 192 + c * 16 + drow) * 1024 + sgr;
            gdst0[si] = As + c * 1024 + lane * 16;
            tsz[si]   = ATILE_B;
        } else if (c < 28) {
            int b = c - 12;
            gsrc[si]  = sb + (size_t)(it * 256 + b * 16 + drow) * 1024 + sgr;
            gdst0[si] = Bs + b * 1024 + lane * 16;
            tsz[si]   = BTILE_B;
        }
    }

    // ds_read addressing (bytes): row*64 + (g^h(row))*16 + (kgrp&1)*8,
    // g = k2*2 + (kgrp>>1), h(row) = (row>>1)&3 = (l15>>1)&3 (bases %16==0).
    // k2=1 address = k2=0 address ^ 32.
    const int hh = (l15 >> 1) & 3;
    const int slot0 = (((kgrp >> 1) ^ hh) * 16) + (kgrp & 1) * 8;
    int abase[6];
#pragma unroll
    for (int rf = 0; rf < 6; ++rf)
        abase[rf] = (wr * 96 + rf * 16 + l15) * 64 + slot0;
    int bbase[4];
#pragma unroll
    for (int cf = 0; cf < 4; ++cf)
        bbase[cf] = (wc * 64 + cf * 16 + l15) * 64 + slot0;

    f32x4 acc[6][4] = {};

    // prologue: stage tile 0 into buffer 0
#pragma unroll
    for (int si = 0; si < 4; ++si) {
        int c = wid + si * 8;
        if (c < 28) gload16(gsrc[si], gdst0[si]);
    }
    asm volatile("s_waitcnt vmcnt(0)" ::: "memory");
    __builtin_amdgcn_s_barrier();

#pragma unroll 2
    for (int kt = 0; kt < 16; ++kt) {
        const int cur = kt & 1;
        const unsigned char* Ac = As + cur * ATILE_B;
        const unsigned char* Bc = Bs + cur * BTILE_B;

        // issue ALL reads for tile kt (both k2 slices): 20 ds_read_b64
        long afr[2][6], bfr[2][4];
#pragma unroll
        for (int k2 = 0; k2 < 2; ++k2) {
#pragma unroll
            for (int rf = 0; rf < 6; ++rf)
                afr[k2][rf] = *reinterpret_cast<const long*>(Ac + (abase[rf] ^ (k2 * 32)));
#pragma unroll
            for (int cf = 0; cf < 4; ++cf)
                bfr[k2][cf] = *reinterpret_cast<const long*>(Bc + (bbase[cf] ^ (k2 * 32)));
        }

        // stage tile kt+1 into the other buffer
        if (kt < 15) {
            const int ko = (kt + 1) * 64;
            const int nb = cur ^ 1;
#pragma unroll
            for (int si = 0; si < 4; ++si) {
                int c = wid + si * 8;
                if (c < 28) gload16(gsrc[si] + ko, gdst0[si] + nb * tsz[si]);
            }
        }

        // MFMAs: no explicit lgkm drain (compiler emits counted lgkmcnt)
        __builtin_amdgcn_s_setprio(1);
#pragma unroll
        for (int k2 = 0; k2 < 2; ++k2)
#pragma unroll
            for (int rf = 0; rf < 6; ++rf)
#pragma unroll
                for (int cf = 0; cf < 4; ++cf)
                    acc[rf][cf] = __builtin_amdgcn_mfma_f32_16x16x32_fp8_fp8(
                        afr[k2][rf], bfr[k2][cf], acc[rf][cf], 0, 0, 0);
        __builtin_amdgcn_s_setprio(0);

        if (kt < 15) {
            asm volatile("s_waitcnt vmcnt(0)" ::: "memory");  // tile kt+1 staged
            __builtin_amdgcn_s_barrier();                     // dbuf handoff
        }
    }

    // Epilogue: wave (wr,wc) owns caption i = it*4+wc, images j = jt*4 + wr*2 + {0,1}.
    // C frag layout (shape-determined, dtype-independent): col=l15, row=kgrp*4+e.
    const int i_cap = it * 4 + wc;
    const int nw = s_l[i_cap];
    const float inv = 1.0f / (float)nw;
#pragma unroll
    for (int h = 0; h < 2; ++h) {       // image half: frags rf = h*3 .. h*3+2 (48 rows)
        float sum = 0.0f;
#pragma unroll
        for (int cf = 0; cf < 4; ++cf) {
            float m = acc[h * 3][cf][0];
#pragma unroll
            for (int rf = h * 3; rf < h * 3 + 3; ++rf)
#pragma unroll
                for (int e = 0; e < 4; ++e)
                    m = fmaxf(m, acc[rf][cf][e]);
            m = fmaxf(m, __shfl_xor(m, 16));
            m = fmaxf(m, __shfl_xor(m, 32));
            int wv = cf * 16 + l15;
            if (wv < nw) sum += m;
        }
        sum += __shfl_xor(sum, 1);
        sum += __shfl_xor(sum, 2);
        sum += __shfl_xor(sum, 4);
        sum += __shfl_xor(sum, 8);
        if (lane == 0) {
            int j_img = jt * 4 + wr * 2 + h;
            S[j_img * B_SZ + i_cap] = sum * inv;
        }
    }
}

// Contrastive loss over the 128x128 score matrix, single block
__global__ __launch_bounds__(256) void loss_kernel(
        const float* __restrict__ S, float* __restrict__ out) {
    __shared__ float diag[B_SZ];
    __shared__ float red[256];
    int t = threadIdx.x;
    if (t < B_SZ) diag[t] = S[t * (B_SZ + 1)];
    __syncthreads();
    float acc = 0.0f;
    for (int idx = t; idx < B_SZ * B_SZ; idx += 256) {
        int a = idx >> 7, b = idx & (B_SZ - 1);
        if (a != b) {
            float v = S[idx];
            acc += fmaxf(MARGIN + v - diag[a], 0.0f)
                 + fmaxf(MARGIN + v - diag[b], 0.0f);
        }
    }
    red[t] = acc;
    __syncthreads();
    for (int s = 128; s > 0; s >>= 1) {
        if (t < s) red[t] += red[t + s];
        __syncthreads();
    }
    if (t == 0) out[0] = red[0];
}

extern "C" void kernel_launch(void* const* d_in, const int* in_sizes, int n_in,
                              void* d_out, int out_size, void* d_ws, size_t ws_size,
                              hipStream_t stream) {
    const float* im  = (const float*)d_in[0];
    const float* s   = (const float*)d_in[1];
    const int*   s_l = (const int*)d_in[2];
    // d_in[3] (x) unused by the math

    const int n_im_pad = B_SZ * RP_SZ * D_SZ;   // 6,291,456 fp8 bytes
    const int n_s_pad  = B_SZ * WP_SZ * D_SZ;   // 8,388,608 fp8 bytes

    unsigned char* imb = (unsigned char*)d_ws;
    unsigned char* sb  = imb + n_im_pad;
    float* S = (float*)(sb + n_s_pad);          // 128*128 floats

    const int ngran = (n_im_pad + n_s_pad) / 16;   // 16-B granules
    convert_fp8_kernel<<<(ngran + 255) / 256, 256, 0, stream>>>(im, s, imb, sb);

    scores_kernel<<<1024, 512, 0, stream>>>(imb, sb, s_l, S);

    loss_kernel<<<1, 256, 0, stream>>>(S, (float*)d_out);
}